// Round 3
// baseline (1192.343 us; speedup 1.0000x reference)
//
#include <hip/hip_runtime.h>
#include <cstdint>

#define NN 50000
#define NE 640000
#define DIM 128

// ---------------------------------------------------------------- degree
__global__ __launch_bounds__(256) void k_degree(const int* __restrict__ dst,
                                                float* __restrict__ deg) {
    int i = blockIdx.x * 256 + threadIdx.x;
    if (i < NE) atomicAdd(&deg[dst[i]], 1.0f);
}

// deg -> dinv = rsqrt(deg + 1)   (+1 = self loop; always > 0)
__global__ __launch_bounds__(256) void k_dinv(float* __restrict__ deg) {
    int i = blockIdx.x * 256 + threadIdx.x;
    if (i < NN) deg[i] = rsqrtf(deg[i] + 1.0f);
}

// ---------------------------------------------------------------- h = x @ W
// 256 threads/block, 32 rows/block. W (64KB) + 32 x-rows (16KB) in LDS.
// thread -> (row slot rq = tid>>5, col group cg = tid&31 covering 4 cols).
__global__ __launch_bounds__(256) void k_gemm(const float* __restrict__ x,
                                              const float* __restrict__ W,
                                              float* __restrict__ h) {
    __shared__ float Ws[DIM * DIM];   // 64 KB, row-major [k][c]
    __shared__ float xs[32 * DIM];    // 16 KB
    const int tid = threadIdx.x;
    const int row0 = blockIdx.x * 32;

    for (int i = tid; i < DIM * DIM / 4; i += 256)
        reinterpret_cast<float4*>(Ws)[i] = reinterpret_cast<const float4*>(W)[i];
    for (int i = tid; i < 32 * DIM / 4; i += 256) {
        int r = row0 + i / (DIM / 4);
        float4 v = make_float4(0.f, 0.f, 0.f, 0.f);
        if (r < NN)
            v = reinterpret_cast<const float4*>(x)[(size_t)r * (DIM / 4) + (i & (DIM / 4 - 1))];
        reinterpret_cast<float4*>(xs)[i] = v;
    }
    __syncthreads();

    const int cg = tid & 31;   // columns cg*4 .. cg*4+3
    const int rq = tid >> 5;   // 0..7
    for (int rr = 0; rr < 32; rr += 8) {
        const int r = row0 + rr + rq;
        const float* xr = xs + (rr + rq) * DIM;
        float4 acc = make_float4(0.f, 0.f, 0.f, 0.f);
        #pragma unroll 8
        for (int k = 0; k < DIM; ++k) {
            const float xv = xr[k];                                        // LDS broadcast
            const float4 w = reinterpret_cast<const float4*>(Ws + k * DIM)[cg];  // conflict-free b128
            acc.x += xv * w.x; acc.y += xv * w.y;
            acc.z += xv * w.z; acc.w += xv * w.w;
        }
        if (r < NN)
            reinterpret_cast<float4*>(h)[(size_t)r * (DIM / 4) + cg] = acc;
    }
}

// ---------------------------------------------------------------- scatter-add
// 32 lanes per edge, one float4 per lane; 8 edges per 256-thread block.
__global__ __launch_bounds__(256) void k_scatter(const int* __restrict__ src,
                                                 const int* __restrict__ dst,
                                                 const float* __restrict__ h,
                                                 const float* __restrict__ dinv,
                                                 float* __restrict__ out) {
    const int t = blockIdx.x * 256 + threadIdx.x;
    const int e = t >> 5;
    if (e >= NE) return;
    const int lane = t & 31;
    const int s = src[e];
    const int d = dst[e];
    const float norm = dinv[s] * dinv[d];
    const float4 v = reinterpret_cast<const float4*>(h + (size_t)s * DIM)[lane];
    float* o = out + (size_t)d * DIM + lane * 4;
    atomicAdd(o + 0, v.x * norm);
    atomicAdd(o + 1, v.y * norm);
    atomicAdd(o + 2, v.z * norm);
    atomicAdd(o + 3, v.w * norm);
}

// ---------------------------------------------------------------- finalize
// out = relu(out + h*dinv^2 (self loop) + bias), in place, one float4/thread.
__global__ __launch_bounds__(256) void k_finalize(const float* __restrict__ h,
                                                  const float* __restrict__ dinv,
                                                  const float* __restrict__ bias,
                                                  float* __restrict__ out) {
    const int t = blockIdx.x * 256 + threadIdx.x;
    if (t >= NN * (DIM / 4)) return;
    const int n = t / (DIM / 4);
    const int c4 = t & (DIM / 4 - 1);
    const float di = dinv[n];
    const float sn = di * di;
    const float4 hv = reinterpret_cast<const float4*>(h)[t];
    const float4 bv = reinterpret_cast<const float4*>(bias)[c4];
    float4 ov = reinterpret_cast<float4*>(out)[t];
    ov.x = fmaxf(fmaf(hv.x, sn, ov.x) + bv.x, 0.f);
    ov.y = fmaxf(fmaf(hv.y, sn, ov.y) + bv.y, 0.f);
    ov.z = fmaxf(fmaf(hv.z, sn, ov.z) + bv.z, 0.f);
    ov.w = fmaxf(fmaf(hv.w, sn, ov.w) + bv.w, 0.f);
    reinterpret_cast<float4*>(out)[t] = ov;
}

// ----------------------------------------------------------------
extern "C" void kernel_launch(void* const* d_in, const int* in_sizes, int n_in,
                              void* d_out, int out_size, void* d_ws, size_t ws_size,
                              hipStream_t stream) {
    const float* x  = (const float*)d_in[0];
    const int*   ei = (const int*)d_in[1];   // [2, NE] -> src row then dst row
    const float* W  = (const float*)d_in[2];
    const float* b  = (const float*)d_in[3];
    float* out = (float*)d_out;

    const int* src = ei;
    const int* dst = ei + NE;

    // workspace layout: h [NN*DIM f32] | deg/dinv [NN f32]   (~25.8 MB)
    float* h   = (float*)d_ws;
    float* deg = h + (size_t)NN * DIM;

    hipMemsetAsync(deg, 0, NN * sizeof(float), stream);
    hipMemsetAsync(out, 0, (size_t)NN * DIM * sizeof(float), stream);

    k_degree<<<(NE + 255) / 256, 256, 0, stream>>>(dst, deg);
    k_gemm<<<(NN + 31) / 32, 256, 0, stream>>>(x, W, h);
    k_dinv<<<(NN + 255) / 256, 256, 0, stream>>>(deg);
    k_scatter<<<(NE * 32 + 255) / 256, 256, 0, stream>>>(src, dst, h, deg, out);
    k_finalize<<<(NN * (DIM / 4) + 255) / 256, 256, 0, stream>>>(h, deg, b, out);
}

// Round 4
// 281.724 us; speedup vs baseline: 4.2323x; 4.2323x over previous
//
#include <hip/hip_runtime.h>
#include <cstdint>

#define NN 50000
#define NE 640000
#define DIM 128
#define SCAN_T 256
#define CHUNK ((NN + SCAN_T - 1) / SCAN_T)   // 196

// ---------------------------------------------------------------- histogram (int)
__global__ __launch_bounds__(256) void k_hist(const int* __restrict__ dst,
                                              int* __restrict__ cnt) {
    int i = blockIdx.x * 256 + threadIdx.x;
    if (i < NE) atomicAdd(&cnt[dst[i]], 1);
}

// dinv = rsqrt(cnt + 1)   (+1 = self loop; always > 0)
__global__ __launch_bounds__(256) void k_dinv(const int* __restrict__ cnt,
                                              float* __restrict__ dinv) {
    int i = blockIdx.x * 256 + threadIdx.x;
    if (i < NN) dinv[i] = rsqrtf((float)cnt[i] + 1.0f);
}

// ---------------------------------------------------------------- single-block scan
// cnt[n] (histogram) -> row_ptr[n] = exclusive prefix; cnt[n] overwritten with the
// same value to serve as the fill cursor. row_ptr[NN] = NE.
__global__ __launch_bounds__(SCAN_T) void k_scan(int* __restrict__ cnt,
                                                 int* __restrict__ row_ptr) {
    __shared__ int part[SCAN_T];
    const int tid = threadIdx.x;
    const int lo = tid * CHUNK;
    const int hi = min(lo + CHUNK, NN);

    int sum = 0;
    #pragma unroll 4
    for (int i = lo; i < hi; ++i) sum += cnt[i];
    part[tid] = sum;
    __syncthreads();
    for (int off = 1; off < SCAN_T; off <<= 1) {
        int v = (tid >= off) ? part[tid - off] : 0;
        __syncthreads();
        part[tid] += v;
        __syncthreads();
    }
    int run = part[tid] - sum;   // exclusive prefix of this thread's chunk
    for (int i = lo; i < hi; ++i) {
        int v = cnt[i];
        row_ptr[i] = run;
        cnt[i] = run;            // becomes fill cursor
        run += v;
    }
    if (tid == SCAN_T - 1) row_ptr[NN] = part[SCAN_T - 1];
}

// ---------------------------------------------------------------- bucket fill
__global__ __launch_bounds__(256) void k_fill(const int* __restrict__ src,
                                              const int* __restrict__ dst,
                                              int* __restrict__ cursor,
                                              int* __restrict__ srt) {
    int i = blockIdx.x * 256 + threadIdx.x;
    if (i < NE) {
        int pos = atomicAdd(&cursor[dst[i]], 1);
        srt[pos] = src[i];
    }
}

// ---------------------------------------------------------------- h = x @ W
// 256 threads/block, 32 rows/block. W (64KB) + 32 x-rows (16KB) in LDS.
__global__ __launch_bounds__(256) void k_gemm(const float* __restrict__ x,
                                              const float* __restrict__ W,
                                              float* __restrict__ h) {
    __shared__ float Ws[DIM * DIM];   // 64 KB, row-major [k][c]
    __shared__ float xs[32 * DIM];    // 16 KB
    const int tid = threadIdx.x;
    const int row0 = blockIdx.x * 32;

    for (int i = tid; i < DIM * DIM / 4; i += 256)
        reinterpret_cast<float4*>(Ws)[i] = reinterpret_cast<const float4*>(W)[i];
    for (int i = tid; i < 32 * DIM / 4; i += 256) {
        int r = row0 + i / (DIM / 4);
        float4 v = make_float4(0.f, 0.f, 0.f, 0.f);
        if (r < NN)
            v = reinterpret_cast<const float4*>(x)[(size_t)r * (DIM / 4) + (i & (DIM / 4 - 1))];
        reinterpret_cast<float4*>(xs)[i] = v;
    }
    __syncthreads();

    const int cg = tid & 31;   // columns cg*4 .. cg*4+3
    const int rq = tid >> 5;   // 0..7
    for (int rr = 0; rr < 32; rr += 8) {
        const int r = row0 + rr + rq;
        const float* xr = xs + (rr + rq) * DIM;
        float4 acc = make_float4(0.f, 0.f, 0.f, 0.f);
        #pragma unroll 8
        for (int k = 0; k < DIM; ++k) {
            const float xv = xr[k];
            const float4 w = reinterpret_cast<const float4*>(Ws + k * DIM)[cg];
            acc.x += xv * w.x; acc.y += xv * w.y;
            acc.z += xv * w.z; acc.w += xv * w.w;
        }
        if (r < NN)
            reinterpret_cast<float4*>(h)[(size_t)r * (DIM / 4) + cg] = acc;
    }
}

// ---------------------------------------------------------------- gather + epilogue
// 32 lanes per dst node (one float4/lane covers DIM=128); 8 nodes per block.
// acc = h[n]*dinv[n]^2 (self loop) + sum_{s in bucket} dinv[s]*dinv[n]*h[s];
// out = relu(acc + bias). Single coalesced write; zero fp32 atomics.
__global__ __launch_bounds__(256) void k_gather(const int* __restrict__ row_ptr,
                                                const int* __restrict__ srt,
                                                const float* __restrict__ h,
                                                const float* __restrict__ dinv,
                                                const float* __restrict__ bias,
                                                float* __restrict__ out) {
    const int t = blockIdx.x * 256 + threadIdx.x;
    const int n = t >> 5;
    if (n >= NN) return;
    const int lane = t & 31;
    const float4* __restrict__ h4 = reinterpret_cast<const float4*>(h);

    const float did = dinv[n];
    const float sn = did * did;
    float4 hv = h4[(size_t)n * 32 + lane];
    float4 acc = make_float4(hv.x * sn, hv.y * sn, hv.z * sn, hv.w * sn);

    int p = row_ptr[n];
    const int pe = row_ptr[n + 1];
    // 2-deep unroll: two independent 512B gathers in flight
    for (; p + 1 < pe; p += 2) {
        const int s0 = srt[p], s1 = srt[p + 1];
        const float n0 = dinv[s0] * did;
        const float n1 = dinv[s1] * did;
        const float4 v0 = h4[(size_t)s0 * 32 + lane];
        const float4 v1 = h4[(size_t)s1 * 32 + lane];
        acc.x += n0 * v0.x + n1 * v1.x;
        acc.y += n0 * v0.y + n1 * v1.y;
        acc.z += n0 * v0.z + n1 * v1.z;
        acc.w += n0 * v0.w + n1 * v1.w;
    }
    if (p < pe) {
        const int s0 = srt[p];
        const float n0 = dinv[s0] * did;
        const float4 v0 = h4[(size_t)s0 * 32 + lane];
        acc.x += n0 * v0.x; acc.y += n0 * v0.y;
        acc.z += n0 * v0.z; acc.w += n0 * v0.w;
    }

    const float4 bv = reinterpret_cast<const float4*>(bias)[lane];
    acc.x = fmaxf(acc.x + bv.x, 0.f);
    acc.y = fmaxf(acc.y + bv.y, 0.f);
    acc.z = fmaxf(acc.z + bv.z, 0.f);
    acc.w = fmaxf(acc.w + bv.w, 0.f);
    reinterpret_cast<float4*>(out)[(size_t)n * 32 + lane] = acc;
}

// ----------------------------------------------------------------
extern "C" void kernel_launch(void* const* d_in, const int* in_sizes, int n_in,
                              void* d_out, int out_size, void* d_ws, size_t ws_size,
                              hipStream_t stream) {
    const float* x  = (const float*)d_in[0];
    const int*   ei = (const int*)d_in[1];   // [2, NE]: src row then dst row
    const float* W  = (const float*)d_in[2];
    const float* b  = (const float*)d_in[3];
    float* out = (float*)d_out;

    const int* src = ei;
    const int* dst = ei + NE;

    // workspace layout (~28.8 MB):
    // h [NN*DIM f32] | dinv [NN f32] | cnt/cursor [NN i32] | row_ptr [NN+2 i32] | srt [NE i32]
    float* h       = (float*)d_ws;
    float* dinv    = h + (size_t)NN * DIM;
    int*   cnt     = (int*)(dinv + NN);
    int*   row_ptr = cnt + NN;
    int*   srt     = row_ptr + NN + 2;

    hipMemsetAsync(cnt, 0, NN * sizeof(int), stream);

    k_hist<<<(NE + 255) / 256, 256, 0, stream>>>(dst, cnt);
    k_dinv<<<(NN + 255) / 256, 256, 0, stream>>>(cnt, dinv);
    k_scan<<<1, SCAN_T, 0, stream>>>(cnt, row_ptr);
    k_fill<<<(NE + 255) / 256, 256, 0, stream>>>(src, dst, cnt, srt);
    k_gemm<<<(NN + 31) / 32, 256, 0, stream>>>(x, W, h);
    k_gather<<<(NN * 32 + 255) / 256, 256, 0, stream>>>(row_ptr, srt, h, dinv, b, out);
}

// Round 5
// 181.875 us; speedup vs baseline: 6.5559x; 1.5490x over previous
//
#include <hip/hip_runtime.h>
#include <cstdint>

#define NN 50000
#define NE 640000
#define DIM 128
#define NB ((NN + 255) / 256)   // 196 scan blocks

// ---------------------------------------------------------------- histogram (int)
__global__ __launch_bounds__(256) void k_hist(const int* __restrict__ dst,
                                              int* __restrict__ cnt) {
    int i = blockIdx.x * 256 + threadIdx.x;
    if (i < NE) atomicAdd(&cnt[dst[i]], 1);
}

// ---------------------------------------------------------------- scan phase A
// Block-local exclusive scan of cnt; local prefix -> row_ptr, block total ->
// partials. Fused: dinv = rsqrt(cnt + 1)  (+1 = self loop).
__global__ __launch_bounds__(256) void k_scanA(const int* __restrict__ cnt,
                                               int* __restrict__ row_ptr,
                                               int* __restrict__ partials,
                                               float* __restrict__ dinv) {
    __shared__ int sh[256];
    const int tid = threadIdx.x;
    const int i = blockIdx.x * 256 + tid;
    const int v = (i < NN) ? cnt[i] : 0;
    if (i < NN) dinv[i] = rsqrtf((float)v + 1.0f);

    sh[tid] = v;
    __syncthreads();
    #pragma unroll
    for (int off = 1; off < 256; off <<= 1) {
        int t = (tid >= off) ? sh[tid - off] : 0;
        __syncthreads();
        sh[tid] += t;
        __syncthreads();
    }
    if (i < NN) row_ptr[i] = sh[tid] - v;          // local exclusive prefix
    if (tid == 255) partials[blockIdx.x] = sh[255]; // block total
}

// ---------------------------------------------------------------- scan phase B
// Single block scans the NB (=196) block totals, exclusive, in place.
__global__ __launch_bounds__(256) void k_scanB(int* __restrict__ partials) {
    __shared__ int sh[256];
    const int tid = threadIdx.x;
    const int v = (tid < NB) ? partials[tid] : 0;
    sh[tid] = v;
    __syncthreads();
    #pragma unroll
    for (int off = 1; off < 256; off <<= 1) {
        int t = (tid >= off) ? sh[tid - off] : 0;
        __syncthreads();
        sh[tid] += t;
        __syncthreads();
    }
    if (tid < NB) partials[tid] = sh[tid] - v;
}

// ---------------------------------------------------------------- scan phase C
// Add block offsets; emit final row_ptr and the bucket-fill cursor.
__global__ __launch_bounds__(256) void k_scanC(int* __restrict__ row_ptr,
                                               const int* __restrict__ partials,
                                               int* __restrict__ cursor) {
    const int i = blockIdx.x * 256 + threadIdx.x;
    if (i < NN) {
        const int rp = row_ptr[i] + partials[blockIdx.x];
        row_ptr[i] = rp;
        cursor[i] = rp;
    }
    if (i == 0) row_ptr[NN] = NE;
}

// ---------------------------------------------------------------- bucket fill
__global__ __launch_bounds__(256) void k_fill(const int* __restrict__ src,
                                              const int* __restrict__ dst,
                                              int* __restrict__ cursor,
                                              int* __restrict__ srt) {
    int i = blockIdx.x * 256 + threadIdx.x;
    if (i < NE) {
        int pos = atomicAdd(&cursor[dst[i]], 1);
        srt[pos] = src[i];
    }
}

// ---------------------------------------------------------------- h = x @ W
// 256 threads/block, 32 rows/block. W (64KB) + 32 x-rows (16KB) in LDS.
__global__ __launch_bounds__(256) void k_gemm(const float* __restrict__ x,
                                              const float* __restrict__ W,
                                              float* __restrict__ h) {
    __shared__ float Ws[DIM * DIM];   // 64 KB, row-major [k][c]
    __shared__ float xs[32 * DIM];    // 16 KB
    const int tid = threadIdx.x;
    const int row0 = blockIdx.x * 32;

    for (int i = tid; i < DIM * DIM / 4; i += 256)
        reinterpret_cast<float4*>(Ws)[i] = reinterpret_cast<const float4*>(W)[i];
    for (int i = tid; i < 32 * DIM / 4; i += 256) {
        int r = row0 + i / (DIM / 4);
        float4 v = make_float4(0.f, 0.f, 0.f, 0.f);
        if (r < NN)
            v = reinterpret_cast<const float4*>(x)[(size_t)r * (DIM / 4) + (i & (DIM / 4 - 1))];
        reinterpret_cast<float4*>(xs)[i] = v;
    }
    __syncthreads();

    const int cg = tid & 31;   // columns cg*4 .. cg*4+3
    const int rq = tid >> 5;   // 0..7
    for (int rr = 0; rr < 32; rr += 8) {
        const int r = row0 + rr + rq;
        const float* xr = xs + (rr + rq) * DIM;
        float4 acc = make_float4(0.f, 0.f, 0.f, 0.f);
        #pragma unroll 8
        for (int k = 0; k < DIM; ++k) {
            const float xv = xr[k];
            const float4 w = reinterpret_cast<const float4*>(Ws + k * DIM)[cg];
            acc.x += xv * w.x; acc.y += xv * w.y;
            acc.z += xv * w.z; acc.w += xv * w.w;
        }
        if (r < NN)
            reinterpret_cast<float4*>(h)[(size_t)r * (DIM / 4) + cg] = acc;
    }
}

// ---------------------------------------------------------------- gather + epilogue
// 32 lanes per dst node (one float4/lane covers DIM=128); 8 nodes per block.
// acc = h[n]*dinv[n]^2 (self loop) + sum_{s in bucket} dinv[s]*dinv[n]*h[s];
// out = relu(acc + bias). Single coalesced write; zero fp32 atomics.
__global__ __launch_bounds__(256) void k_gather(const int* __restrict__ row_ptr,
                                                const int* __restrict__ srt,
                                                const float* __restrict__ h,
                                                const float* __restrict__ dinv,
                                                const float* __restrict__ bias,
                                                float* __restrict__ out) {
    const int t = blockIdx.x * 256 + threadIdx.x;
    const int n = t >> 5;
    if (n >= NN) return;
    const int lane = t & 31;
    const float4* __restrict__ h4 = reinterpret_cast<const float4*>(h);

    const float did = dinv[n];
    const float sn = did * did;
    float4 hv = h4[(size_t)n * 32 + lane];
    float4 acc = make_float4(hv.x * sn, hv.y * sn, hv.z * sn, hv.w * sn);

    int p = row_ptr[n];
    const int pe = row_ptr[n + 1];
    // 2-deep unroll: two independent 512B gathers in flight
    for (; p + 1 < pe; p += 2) {
        const int s0 = srt[p], s1 = srt[p + 1];
        const float n0 = dinv[s0] * did;
        const float n1 = dinv[s1] * did;
        const float4 v0 = h4[(size_t)s0 * 32 + lane];
        const float4 v1 = h4[(size_t)s1 * 32 + lane];
        acc.x += n0 * v0.x + n1 * v1.x;
        acc.y += n0 * v0.y + n1 * v1.y;
        acc.z += n0 * v0.z + n1 * v1.z;
        acc.w += n0 * v0.w + n1 * v1.w;
    }
    if (p < pe) {
        const int s0 = srt[p];
        const float n0 = dinv[s0] * did;
        const float4 v0 = h4[(size_t)s0 * 32 + lane];
        acc.x += n0 * v0.x; acc.y += n0 * v0.y;
        acc.z += n0 * v0.z; acc.w += n0 * v0.w;
    }

    const float4 bv = reinterpret_cast<const float4*>(bias)[lane];
    acc.x = fmaxf(acc.x + bv.x, 0.f);
    acc.y = fmaxf(acc.y + bv.y, 0.f);
    acc.z = fmaxf(acc.z + bv.z, 0.f);
    acc.w = fmaxf(acc.w + bv.w, 0.f);
    reinterpret_cast<float4*>(out)[(size_t)n * 32 + lane] = acc;
}

// ----------------------------------------------------------------
extern "C" void kernel_launch(void* const* d_in, const int* in_sizes, int n_in,
                              void* d_out, int out_size, void* d_ws, size_t ws_size,
                              hipStream_t stream) {
    const float* x  = (const float*)d_in[0];
    const int*   ei = (const int*)d_in[1];   // [2, NE]: src row then dst row
    const float* W  = (const float*)d_in[2];
    const float* b  = (const float*)d_in[3];
    float* out = (float*)d_out;

    const int* src = ei;
    const int* dst = ei + NE;

    // workspace layout (~28.8 MB):
    // h [NN*DIM f32] | dinv [NN f32] | cnt/cursor [NN i32] | row_ptr [NN+2 i32]
    // | partials [NB i32] | srt [NE i32]
    float* h        = (float*)d_ws;
    float* dinv     = h + (size_t)NN * DIM;
    int*   cnt      = (int*)(dinv + NN);
    int*   row_ptr  = cnt + NN;
    int*   partials = row_ptr + NN + 2;
    int*   srt      = partials + NB;

    hipMemsetAsync(cnt, 0, NN * sizeof(int), stream);

    k_hist<<<(NE + 255) / 256, 256, 0, stream>>>(dst, cnt);
    k_scanA<<<NB, 256, 0, stream>>>(cnt, row_ptr, partials, dinv);
    k_scanB<<<1, 256, 0, stream>>>(partials);
    k_scanC<<<NB, 256, 0, stream>>>(row_ptr, partials, cnt);
    k_fill<<<(NE + 255) / 256, 256, 0, stream>>>(src, dst, cnt, srt);
    k_gemm<<<(NN + 31) / 32, 256, 0, stream>>>(x, W, h);
    k_gather<<<(NN * 32 + 255) / 256, 256, 0, stream>>>(row_ptr, srt, h, dinv, b, out);
}

// Round 6
// 146.574 us; speedup vs baseline: 8.1347x; 1.2408x over previous
//
#include <hip/hip_runtime.h>
#include <cstdint>

#define NN 50000
#define NE 640000
#define DIM 128
#define NB ((NN + 255) / 256)   // 196 scan blocks

typedef __attribute__((ext_vector_type(8))) short bf16x8;
typedef __attribute__((ext_vector_type(4))) float f32x4;

static __device__ __forceinline__ short f2bf(float f) {
    union { float f; uint32_t u; } v; v.f = f;
    uint32_t r = v.u + 0x7FFFu + ((v.u >> 16) & 1u);   // RNE
    return (short)(r >> 16);
}

// ---------------------------------------------------------------- histogram (int)
__global__ __launch_bounds__(256) void k_hist(const int* __restrict__ dst,
                                              int* __restrict__ cnt) {
    int i = blockIdx.x * 256 + threadIdx.x;
    if (i < NE) atomicAdd(&cnt[dst[i]], 1);
}

// ---------------------------------------------------------------- scan phase A
__global__ __launch_bounds__(256) void k_scanA(const int* __restrict__ cnt,
                                               int* __restrict__ row_ptr,
                                               int* __restrict__ partials,
                                               float* __restrict__ dinv) {
    __shared__ int sh[256];
    const int tid = threadIdx.x;
    const int i = blockIdx.x * 256 + tid;
    const int v = (i < NN) ? cnt[i] : 0;
    if (i < NN) dinv[i] = rsqrtf((float)v + 1.0f);

    sh[tid] = v;
    __syncthreads();
    #pragma unroll
    for (int off = 1; off < 256; off <<= 1) {
        int t = (tid >= off) ? sh[tid - off] : 0;
        __syncthreads();
        sh[tid] += t;
        __syncthreads();
    }
    if (i < NN) row_ptr[i] = sh[tid] - v;
    if (tid == 255) partials[blockIdx.x] = sh[255];
}

// ---------------------------------------------------------------- scan phase B
__global__ __launch_bounds__(256) void k_scanB(int* __restrict__ partials) {
    __shared__ int sh[256];
    const int tid = threadIdx.x;
    const int v = (tid < NB) ? partials[tid] : 0;
    sh[tid] = v;
    __syncthreads();
    #pragma unroll
    for (int off = 1; off < 256; off <<= 1) {
        int t = (tid >= off) ? sh[tid - off] : 0;
        __syncthreads();
        sh[tid] += t;
        __syncthreads();
    }
    if (tid < NB) partials[tid] = sh[tid] - v;
}

// ---------------------------------------------------------------- scan phase C
__global__ __launch_bounds__(256) void k_scanC(int* __restrict__ row_ptr,
                                               const int* __restrict__ partials,
                                               int* __restrict__ cursor) {
    const int i = blockIdx.x * 256 + threadIdx.x;
    if (i < NN) {
        const int rp = row_ptr[i] + partials[blockIdx.x];
        row_ptr[i] = rp;
        cursor[i] = rp;
    }
    if (i == 0) row_ptr[NN] = NE;
}

// ---------------------------------------------------------------- bucket fill
__global__ __launch_bounds__(256) void k_fill(const int* __restrict__ src,
                                              const int* __restrict__ dst,
                                              int* __restrict__ cursor,
                                              int* __restrict__ srt) {
    int i = blockIdx.x * 256 + threadIdx.x;
    if (i < NE) {
        int pos = atomicAdd(&cursor[dst[i]], 1);
        srt[pos] = src[i];
    }
}

// ---------------------------------------------------------------- W -> fragment-ordered bf16
// Wf[t], t = (n*4 + kk)*64 + lane: 8 bf16 = W[k0..k0+8)[n*16 + (lane&15)],
// k0 = kk*32 + (lane>>4)*8. Same slot->k bijection as the A-side load below.
__global__ __launch_bounds__(256) void k_wfrag(const float* __restrict__ W,
                                               bf16x8* __restrict__ Wf) {
    const int t = blockIdx.x * 256 + threadIdx.x;
    if (t >= 2048) return;
    const int n = t >> 8;
    const int kk = (t >> 6) & 3;
    const int l = t & 63;
    const int c = n * 16 + (l & 15);
    const int k0 = kk * 32 + (l >> 4) * 8;
    bf16x8 v;
    #pragma unroll
    for (int j = 0; j < 8; ++j) v[j] = f2bf(W[(size_t)(k0 + j) * DIM + c]);
    Wf[t] = v;
}

// ---------------------------------------------------------------- h = x @ W via MFMA
// 4 waves/block, 16 rows/wave (BM=64). Wf staged in LDS (32KB -> 5 blocks/CU).
// A: x fp32 read direct (16 rows x 128B contiguous per wave), bf16-converted
// in-register, all 4 k-step fragments held in VGPRs across the 8 col-tiles.
__global__ __launch_bounds__(256) void k_gemm(const float* __restrict__ x,
                                              const bf16x8* __restrict__ Wf,
                                              float* __restrict__ h) {
    __shared__ bf16x8 Bs[2048];   // 32 KB
    const int tid = threadIdx.x;
    #pragma unroll
    for (int i = 0; i < 8; ++i) Bs[tid + i * 256] = Wf[tid + i * 256];

    const int wave = tid >> 6;
    const int lane = tid & 63;
    const int rbase = blockIdx.x * 64 + wave * 16;
    const int rA = rbase + (lane & 15);          // A-fragment row (m = lane&15)
    const int kg = lane >> 4;                    // k-group 0..3

    bf16x8 a[4];
    if (rA < NN) {
        const float* xr = x + (size_t)rA * DIM + kg * 8;
        #pragma unroll
        for (int kk = 0; kk < 4; ++kk) {
            const float4 f0 = *reinterpret_cast<const float4*>(xr + kk * 32);
            const float4 f1 = *reinterpret_cast<const float4*>(xr + kk * 32 + 4);
            a[kk][0] = f2bf(f0.x); a[kk][1] = f2bf(f0.y);
            a[kk][2] = f2bf(f0.z); a[kk][3] = f2bf(f0.w);
            a[kk][4] = f2bf(f1.x); a[kk][5] = f2bf(f1.y);
            a[kk][6] = f2bf(f1.z); a[kk][7] = f2bf(f1.w);
        }
    } else {
        #pragma unroll
        for (int kk = 0; kk < 4; ++kk) a[kk] = (bf16x8)0;
    }
    __syncthreads();

    const int rC0 = rbase + (lane >> 4) * 4;     // C rows: rC0 + i  (i=0..3)
    const int col = lane & 15;
    #pragma unroll
    for (int n = 0; n < 8; ++n) {
        f32x4 acc = {0.f, 0.f, 0.f, 0.f};
        #pragma unroll
        for (int kk = 0; kk < 4; ++kk) {
            const bf16x8 b = Bs[(n * 4 + kk) * 64 + lane];   // stride-1, conflict-free
            acc = __builtin_amdgcn_mfma_f32_16x16x32_bf16(a[kk], b, acc, 0, 0, 0);
        }
        #pragma unroll
        for (int i = 0; i < 4; ++i) {
            const int r = rC0 + i;
            if (r < NN) h[(size_t)r * DIM + n * 16 + col] = acc[i];
        }
    }
}

// ---------------------------------------------------------------- gather + epilogue
__global__ __launch_bounds__(256) void k_gather(const int* __restrict__ row_ptr,
                                                const int* __restrict__ srt,
                                                const float* __restrict__ h,
                                                const float* __restrict__ dinv,
                                                const float* __restrict__ bias,
                                                float* __restrict__ out) {
    const int t = blockIdx.x * 256 + threadIdx.x;
    const int n = t >> 5;
    if (n >= NN) return;
    const int lane = t & 31;
    const float4* __restrict__ h4 = reinterpret_cast<const float4*>(h);

    const float did = dinv[n];
    const float sn = did * did;
    float4 hv = h4[(size_t)n * 32 + lane];
    float4 acc = make_float4(hv.x * sn, hv.y * sn, hv.z * sn, hv.w * sn);

    int p = row_ptr[n];
    const int pe = row_ptr[n + 1];
    for (; p + 1 < pe; p += 2) {
        const int s0 = srt[p], s1 = srt[p + 1];
        const float n0 = dinv[s0] * did;
        const float n1 = dinv[s1] * did;
        const float4 v0 = h4[(size_t)s0 * 32 + lane];
        const float4 v1 = h4[(size_t)s1 * 32 + lane];
        acc.x += n0 * v0.x + n1 * v1.x;
        acc.y += n0 * v0.y + n1 * v1.y;
        acc.z += n0 * v0.z + n1 * v1.z;
        acc.w += n0 * v0.w + n1 * v1.w;
    }
    if (p < pe) {
        const int s0 = srt[p];
        const float n0 = dinv[s0] * did;
        const float4 v0 = h4[(size_t)s0 * 32 + lane];
        acc.x += n0 * v0.x; acc.y += n0 * v0.y;
        acc.z += n0 * v0.z; acc.w += n0 * v0.w;
    }

    const float4 bv = reinterpret_cast<const float4*>(bias)[lane];
    acc.x = fmaxf(acc.x + bv.x, 0.f);
    acc.y = fmaxf(acc.y + bv.y, 0.f);
    acc.z = fmaxf(acc.z + bv.z, 0.f);
    acc.w = fmaxf(acc.w + bv.w, 0.f);
    reinterpret_cast<float4*>(out)[(size_t)n * 32 + lane] = acc;
}

// ----------------------------------------------------------------
extern "C" void kernel_launch(void* const* d_in, const int* in_sizes, int n_in,
                              void* d_out, int out_size, void* d_ws, size_t ws_size,
                              hipStream_t stream) {
    const float* x  = (const float*)d_in[0];
    const int*   ei = (const int*)d_in[1];   // [2, NE]: src row then dst row
    const float* W  = (const float*)d_in[2];
    const float* b  = (const float*)d_in[3];
    float* out = (float*)d_out;

    const int* src = ei;
    const int* dst = ei + NE;

    // workspace (~28.9 MB):
    // h [NN*DIM f32] | dinv [NN f32] | cnt/cursor [NN i32] | row_ptr [NN+2 i32]
    // | partials [NB i32] | srt [NE i32] | Wf [2048 x 16B]
    float*  h        = (float*)d_ws;
    float*  dinv     = h + (size_t)NN * DIM;
    int*    cnt      = (int*)(dinv + NN);
    int*    row_ptr  = cnt + NN;
    int*    partials = row_ptr + NN + 2;
    int*    srt      = partials + NB;
    bf16x8* Wf       = (bf16x8*)(srt + NE);

    hipMemsetAsync(cnt, 0, NN * sizeof(int), stream);

    k_wfrag<<<8, 256, 0, stream>>>(W, Wf);
    k_hist<<<(NE + 255) / 256, 256, 0, stream>>>(dst, cnt);
    k_scanA<<<NB, 256, 0, stream>>>(cnt, row_ptr, partials, dinv);
    k_scanB<<<1, 256, 0, stream>>>(partials);
    k_scanC<<<NB, 256, 0, stream>>>(row_ptr, partials, cnt);
    k_fill<<<(NE + 255) / 256, 256, 0, stream>>>(src, dst, cnt, srt);
    k_gemm<<<(NN + 63) / 64, 256, 0, stream>>>(x, Wf, h);
    k_gather<<<(NN * 32 + 255) / 256, 256, 0, stream>>>(row_ptr, srt, h, dinv, b, out);
}

// Round 7
// 122.562 us; speedup vs baseline: 9.7285x; 1.1959x over previous
//
#include <hip/hip_runtime.h>
#include <cstdint>

#define NN 50000
#define NE 640000
#define DIM 128
#define NB ((NN + 255) / 256)   // 196 scan blocks

typedef __attribute__((ext_vector_type(8))) short bf16x8;
typedef __attribute__((ext_vector_type(8))) unsigned short u16x8;
typedef __attribute__((ext_vector_type(4))) float f32x4;

static __device__ __forceinline__ short f2bf(float f) {
    union { float f; uint32_t u; } v; v.f = f;
    uint32_t r = v.u + 0x7FFFu + ((v.u >> 16) & 1u);   // RNE
    return (short)(r >> 16);
}
static __device__ __forceinline__ float bf2f(unsigned short u) {
    union { uint32_t u; float f; } v; v.u = ((uint32_t)u) << 16;   // exact
    return v.f;
}

// ---------------------------------------------------------------- histogram (int)
__global__ __launch_bounds__(256) void k_hist(const int* __restrict__ dst,
                                              int* __restrict__ cnt) {
    int i = blockIdx.x * 256 + threadIdx.x;
    if (i < NE) atomicAdd(&cnt[dst[i]], 1);
}

// ---------------------------------------------------------------- scan phase A
// Block-local exclusive scan of cnt -> row_ptr (local), block total -> partials.
// Fused: dinv = rsqrt(cnt + 1)  (+1 = self loop).
__global__ __launch_bounds__(256) void k_scanA(const int* __restrict__ cnt,
                                               int* __restrict__ row_ptr,
                                               int* __restrict__ partials,
                                               float* __restrict__ dinv) {
    __shared__ int sh[256];
    const int tid = threadIdx.x;
    const int i = blockIdx.x * 256 + tid;
    const int v = (i < NN) ? cnt[i] : 0;
    if (i < NN) dinv[i] = rsqrtf((float)v + 1.0f);

    sh[tid] = v;
    __syncthreads();
    #pragma unroll
    for (int off = 1; off < 256; off <<= 1) {
        int t = (tid >= off) ? sh[tid - off] : 0;
        __syncthreads();
        sh[tid] += t;
        __syncthreads();
    }
    if (i < NN) row_ptr[i] = sh[tid] - v;
    if (tid == 255) partials[blockIdx.x] = sh[255];
}

// ---------------------------------------------------------------- scan phase C
// Fused former phase B: every block redundantly scans the NB(=196) partials in
// LDS (cheap), takes its own exclusive offset, emits final row_ptr + cursor.
__global__ __launch_bounds__(256) void k_scanC(int* __restrict__ row_ptr,
                                               const int* __restrict__ partials,
                                               int* __restrict__ cursor) {
    __shared__ int sh[256];
    __shared__ int orig[256];
    const int tid = threadIdx.x;
    const int v = (tid < NB) ? partials[tid] : 0;
    sh[tid] = v;
    orig[tid] = v;
    __syncthreads();
    #pragma unroll
    for (int off = 1; off < 256; off <<= 1) {
        int t = (tid >= off) ? sh[tid - off] : 0;
        __syncthreads();
        sh[tid] += t;
        __syncthreads();
    }
    const int excl = sh[blockIdx.x] - orig[blockIdx.x];   // LDS broadcast reads
    const int i = blockIdx.x * 256 + tid;
    if (i < NN) {
        const int rp = row_ptr[i] + excl;
        row_ptr[i] = rp;
        cursor[i] = rp;
    }
    if (blockIdx.x == 0 && tid == 0) row_ptr[NN] = NE;
}

// ---------------------------------------------------------------- bucket fill
__global__ __launch_bounds__(256) void k_fill(const int* __restrict__ src,
                                              const int* __restrict__ dst,
                                              int* __restrict__ cursor,
                                              int* __restrict__ srt) {
    int i = blockIdx.x * 256 + threadIdx.x;
    if (i < NE) {
        int pos = atomicAdd(&cursor[dst[i]], 1);
        srt[pos] = src[i];
    }
}

// ---------------------------------------------------------------- W -> fragment-ordered bf16
// Wf[t], t = (n*4 + kk)*64 + lane: 8 bf16 = W[k0..k0+8)[n*16 + (lane&15)],
// k0 = kk*32 + (lane>>4)*8. Same slot->k bijection as the A-side load below.
__global__ __launch_bounds__(256) void k_wfrag(const float* __restrict__ W,
                                               bf16x8* __restrict__ Wf) {
    const int t = blockIdx.x * 256 + threadIdx.x;
    if (t >= 2048) return;
    const int n = t >> 8;
    const int kk = (t >> 6) & 3;
    const int l = t & 63;
    const int c = n * 16 + (l & 15);
    const int k0 = kk * 32 + (l >> 4) * 8;
    bf16x8 v;
    #pragma unroll
    for (int j = 0; j < 8; ++j) v[j] = f2bf(W[(size_t)(k0 + j) * DIM + c]);
    Wf[t] = v;
}

// ---------------------------------------------------------------- h = x @ W via MFMA
// 4 waves/block, 16 rows/wave (BM=64). Wf staged in LDS. h stored as bf16.
__global__ __launch_bounds__(256) void k_gemm(const float* __restrict__ x,
                                              const bf16x8* __restrict__ Wf,
                                              unsigned short* __restrict__ h_bf) {
    __shared__ bf16x8 Bs[2048];   // 32 KB
    const int tid = threadIdx.x;
    #pragma unroll
    for (int i = 0; i < 8; ++i) Bs[tid + i * 256] = Wf[tid + i * 256];

    const int wave = tid >> 6;
    const int lane = tid & 63;
    const int rbase = blockIdx.x * 64 + wave * 16;
    const int rA = rbase + (lane & 15);          // A-fragment row (m = lane&15)
    const int kg = lane >> 4;                    // k-group 0..3

    bf16x8 a[4];
    if (rA < NN) {
        const float* xr = x + (size_t)rA * DIM + kg * 8;
        #pragma unroll
        for (int kk = 0; kk < 4; ++kk) {
            const float4 f0 = *reinterpret_cast<const float4*>(xr + kk * 32);
            const float4 f1 = *reinterpret_cast<const float4*>(xr + kk * 32 + 4);
            a[kk][0] = f2bf(f0.x); a[kk][1] = f2bf(f0.y);
            a[kk][2] = f2bf(f0.z); a[kk][3] = f2bf(f0.w);
            a[kk][4] = f2bf(f1.x); a[kk][5] = f2bf(f1.y);
            a[kk][6] = f2bf(f1.z); a[kk][7] = f2bf(f1.w);
        }
    } else {
        #pragma unroll
        for (int kk = 0; kk < 4; ++kk) a[kk] = (bf16x8)0;
    }
    __syncthreads();

    const int rC0 = rbase + (lane >> 4) * 4;     // C rows: rC0 + i  (i=0..3)
    const int col = lane & 15;
    #pragma unroll
    for (int n = 0; n < 8; ++n) {
        f32x4 acc = {0.f, 0.f, 0.f, 0.f};
        #pragma unroll
        for (int kk = 0; kk < 4; ++kk) {
            const bf16x8 b = Bs[(n * 4 + kk) * 64 + lane];   // stride-1, conflict-free
            acc = __builtin_amdgcn_mfma_f32_16x16x32_bf16(a[kk], b, acc, 0, 0, 0);
        }
        #pragma unroll
        for (int i = 0; i < 4; ++i) {
            const int r = rC0 + i;
            if (r < NN)
                h_bf[(size_t)r * DIM + n * 16 + col] = (unsigned short)f2bf(acc[i]);
        }
    }
}

// ---------------------------------------------------------------- gather + epilogue
// 16 lanes per dst node (one ushort8 = 16B/lane covers 8 of 128 cols);
// 4 nodes per wave, 16 nodes per block. fp32 accumulate; single coalesced write.
__global__ __launch_bounds__(256) void k_gather(const int* __restrict__ row_ptr,
                                                const int* __restrict__ srt,
                                                const unsigned short* __restrict__ h_bf,
                                                const float* __restrict__ dinv,
                                                const float* __restrict__ bias,
                                                float* __restrict__ out) {
    const int t = blockIdx.x * 256 + threadIdx.x;
    const int n = t >> 4;
    if (n >= NN) return;
    const int lane = t & 15;                     // columns lane*8 .. lane*8+7
    const u16x8* __restrict__ h8 = reinterpret_cast<const u16x8*>(h_bf);

    const float did = dinv[n];
    const float sn = did * did;
    float acc[8];
    {
        const u16x8 hv = h8[(size_t)n * 16 + lane];
        #pragma unroll
        for (int j = 0; j < 8; ++j) acc[j] = bf2f(hv[j]) * sn;
    }

    int p = row_ptr[n];
    const int pe = row_ptr[n + 1];
    // 2-deep unroll: two independent 256B row gathers in flight
    for (; p + 1 < pe; p += 2) {
        const int s0 = srt[p], s1 = srt[p + 1];
        const float n0 = dinv[s0] * did;
        const float n1 = dinv[s1] * did;
        const u16x8 v0 = h8[(size_t)s0 * 16 + lane];
        const u16x8 v1 = h8[(size_t)s1 * 16 + lane];
        #pragma unroll
        for (int j = 0; j < 8; ++j) acc[j] = fmaf(bf2f(v0[j]), n0, acc[j]);
        #pragma unroll
        for (int j = 0; j < 8; ++j) acc[j] = fmaf(bf2f(v1[j]), n1, acc[j]);
    }
    if (p < pe) {
        const int s0 = srt[p];
        const float n0 = dinv[s0] * did;
        const u16x8 v0 = h8[(size_t)s0 * 16 + lane];
        #pragma unroll
        for (int j = 0; j < 8; ++j) acc[j] = fmaf(bf2f(v0[j]), n0, acc[j]);
    }

    const float4 bv0 = reinterpret_cast<const float4*>(bias)[lane * 2];
    const float4 bv1 = reinterpret_cast<const float4*>(bias)[lane * 2 + 1];
    float4 o0, o1;
    o0.x = fmaxf(acc[0] + bv0.x, 0.f); o0.y = fmaxf(acc[1] + bv0.y, 0.f);
    o0.z = fmaxf(acc[2] + bv0.z, 0.f); o0.w = fmaxf(acc[3] + bv0.w, 0.f);
    o1.x = fmaxf(acc[4] + bv1.x, 0.f); o1.y = fmaxf(acc[5] + bv1.y, 0.f);
    o1.z = fmaxf(acc[6] + bv1.z, 0.f); o1.w = fmaxf(acc[7] + bv1.w, 0.f);
    float4* orow = reinterpret_cast<float4*>(out + (size_t)n * DIM) + lane * 2;
    orow[0] = o0;
    orow[1] = o1;
}

// ----------------------------------------------------------------
extern "C" void kernel_launch(void* const* d_in, const int* in_sizes, int n_in,
                              void* d_out, int out_size, void* d_ws, size_t ws_size,
                              hipStream_t stream) {
    const float* x  = (const float*)d_in[0];
    const int*   ei = (const int*)d_in[1];   // [2, NE]: src row then dst row
    const float* W  = (const float*)d_in[2];
    const float* b  = (const float*)d_in[3];
    float* out = (float*)d_out;

    const int* src = ei;
    const int* dst = ei + NE;

    // workspace (~16.2 MB):
    // h_bf [NN*DIM u16] | dinv [NN f32] | cnt/cursor [NN i32] | row_ptr [NN+4 i32]
    // | partials [NB i32] | srt [NE i32] | Wf [2048 x 16B]  (all 16B-aligned)
    unsigned short* h_bf = (unsigned short*)d_ws;
    float* dinv     = (float*)(h_bf + (size_t)NN * DIM);
    int*   cnt      = (int*)(dinv + NN);
    int*   row_ptr  = cnt + NN;
    int*   partials = row_ptr + NN + 4;
    int*   srt      = partials + NB;
    bf16x8* Wf      = (bf16x8*)(srt + NE);

    hipMemsetAsync(cnt, 0, NN * sizeof(int), stream);

    k_wfrag<<<8, 256, 0, stream>>>(W, Wf);
    k_hist<<<(NE + 255) / 256, 256, 0, stream>>>(dst, cnt);
    k_scanA<<<NB, 256, 0, stream>>>(cnt, row_ptr, partials, dinv);
    k_scanC<<<NB, 256, 0, stream>>>(row_ptr, partials, cnt);
    k_fill<<<(NE + 255) / 256, 256, 0, stream>>>(src, dst, cnt, srt);
    k_gemm<<<(NN + 63) / 64, 256, 0, stream>>>(x, Wf, h_bf);
    k_gather<<<(NN * 16 + 255) / 256, 256, 0, stream>>>(row_ptr, srt, h_bf, dinv, b, out);
}

// Round 8
// 117.902 us; speedup vs baseline: 10.1130x; 1.0395x over previous
//
#include <hip/hip_runtime.h>
#include <cstdint>

#define NN 50000
#define NE 640000
#define DIM 128
#define NB ((NN + 255) / 256)   // 196 scan blocks

typedef __attribute__((ext_vector_type(8))) short bf16x8;
typedef __attribute__((ext_vector_type(8))) unsigned short u16x8;
typedef __attribute__((ext_vector_type(4))) float f32x4;

static __device__ __forceinline__ short f2bf(float f) {
    union { float f; uint32_t u; } v; v.f = f;
    uint32_t r = v.u + 0x7FFFu + ((v.u >> 16) & 1u);   // RNE
    return (short)(r >> 16);
}
static __device__ __forceinline__ float bf2f(unsigned short u) {
    union { uint32_t u; float f; } v; v.u = ((uint32_t)u) << 16;   // exact
    return v.f;
}

// ---------------------------------------------------------------- init
// Fused: zero cnt (12500 int4 stores) + build fragment-ordered bf16 W.
// Wf[t], t = (n*4 + kk)*64 + lane: 8 bf16 = W[k0..k0+8)[n*16 + (lane&15)],
// k0 = kk*32 + (lane>>4)*8. Same slot->k bijection as the A-side load in k_gemm.
__global__ __launch_bounds__(256) void k_init(const float* __restrict__ W,
                                              bf16x8* __restrict__ Wf,
                                              int4* __restrict__ cnt4) {
    const int t = blockIdx.x * 256 + threadIdx.x;
    if (t < NN / 4) cnt4[t] = make_int4(0, 0, 0, 0);
    if (t < 2048) {
        const int n = t >> 8;
        const int kk = (t >> 6) & 3;
        const int l = t & 63;
        const int c = n * 16 + (l & 15);
        const int k0 = kk * 32 + (l >> 4) * 8;
        bf16x8 v;
        #pragma unroll
        for (int j = 0; j < 8; ++j) v[j] = f2bf(W[(size_t)(k0 + j) * DIM + c]);
        Wf[t] = v;
    }
}

// ---------------------------------------------------------------- histogram (int)
__global__ __launch_bounds__(256) void k_hist(const int* __restrict__ dst,
                                              int* __restrict__ cnt) {
    int i = blockIdx.x * 256 + threadIdx.x;
    if (i < NE) atomicAdd(&cnt[dst[i]], 1);
}

// ---------------------------------------------------------------- scan phase A
// Block-local exclusive scan of cnt -> row_ptr (local), block total -> partials.
// Fused: dinv = rsqrt(cnt + 1)  (+1 = self loop).
__global__ __launch_bounds__(256) void k_scanA(const int* __restrict__ cnt,
                                               int* __restrict__ row_ptr,
                                               int* __restrict__ partials,
                                               float* __restrict__ dinv) {
    __shared__ int sh[256];
    const int tid = threadIdx.x;
    const int i = blockIdx.x * 256 + tid;
    const int v = (i < NN) ? cnt[i] : 0;
    if (i < NN) dinv[i] = rsqrtf((float)v + 1.0f);

    sh[tid] = v;
    __syncthreads();
    #pragma unroll
    for (int off = 1; off < 256; off <<= 1) {
        int t = (tid >= off) ? sh[tid - off] : 0;
        __syncthreads();
        sh[tid] += t;
        __syncthreads();
    }
    if (i < NN) row_ptr[i] = sh[tid] - v;
    if (tid == 255) partials[blockIdx.x] = sh[255];
}

// ---------------------------------------------------------------- scan phase C
// Every block redundantly scans the NB(=196) partials in LDS, takes its own
// exclusive offset, emits final row_ptr + cursor.
__global__ __launch_bounds__(256) void k_scanC(int* __restrict__ row_ptr,
                                               const int* __restrict__ partials,
                                               int* __restrict__ cursor) {
    __shared__ int sh[256];
    __shared__ int orig[256];
    const int tid = threadIdx.x;
    const int v = (tid < NB) ? partials[tid] : 0;
    sh[tid] = v;
    orig[tid] = v;
    __syncthreads();
    #pragma unroll
    for (int off = 1; off < 256; off <<= 1) {
        int t = (tid >= off) ? sh[tid - off] : 0;
        __syncthreads();
        sh[tid] += t;
        __syncthreads();
    }
    const int excl = sh[blockIdx.x] - orig[blockIdx.x];   // LDS broadcast reads
    const int i = blockIdx.x * 256 + tid;
    if (i < NN) {
        const int rp = row_ptr[i] + excl;
        row_ptr[i] = rp;
        cursor[i] = rp;
    }
    if (blockIdx.x == 0 && tid == 0) row_ptr[NN] = NE;
}

// ---------------------------------------------------------------- bucket fill
__global__ __launch_bounds__(256) void k_fill(const int* __restrict__ src,
                                              const int* __restrict__ dst,
                                              int* __restrict__ cursor,
                                              int* __restrict__ srt) {
    int i = blockIdx.x * 256 + threadIdx.x;
    if (i < NE) {
        int pos = atomicAdd(&cursor[dst[i]], 1);
        srt[pos] = src[i];
    }
}

// ---------------------------------------------------------------- h = x @ W via MFMA
// 4 waves/block, 16 rows/wave (BM=64). Wf staged in LDS. h stored as bf16.
__global__ __launch_bounds__(256) void k_gemm(const float* __restrict__ x,
                                              const bf16x8* __restrict__ Wf,
                                              unsigned short* __restrict__ h_bf) {
    __shared__ bf16x8 Bs[2048];   // 32 KB
    const int tid = threadIdx.x;
    #pragma unroll
    for (int i = 0; i < 8; ++i) Bs[tid + i * 256] = Wf[tid + i * 256];

    const int wave = tid >> 6;
    const int lane = tid & 63;
    const int rbase = blockIdx.x * 64 + wave * 16;
    const int rA = rbase + (lane & 15);          // A-fragment row (m = lane&15)
    const int kg = lane >> 4;                    // k-group 0..3

    bf16x8 a[4];
    if (rA < NN) {
        const float* xr = x + (size_t)rA * DIM + kg * 8;
        #pragma unroll
        for (int kk = 0; kk < 4; ++kk) {
            const float4 f0 = *reinterpret_cast<const float4*>(xr + kk * 32);
            const float4 f1 = *reinterpret_cast<const float4*>(xr + kk * 32 + 4);
            a[kk][0] = f2bf(f0.x); a[kk][1] = f2bf(f0.y);
            a[kk][2] = f2bf(f0.z); a[kk][3] = f2bf(f0.w);
            a[kk][4] = f2bf(f1.x); a[kk][5] = f2bf(f1.y);
            a[kk][6] = f2bf(f1.z); a[kk][7] = f2bf(f1.w);
        }
    } else {
        #pragma unroll
        for (int kk = 0; kk < 4; ++kk) a[kk] = (bf16x8)0;
    }
    __syncthreads();

    const int rC0 = rbase + (lane >> 4) * 4;     // C rows: rC0 + i  (i=0..3)
    const int col = lane & 15;
    #pragma unroll
    for (int n = 0; n < 8; ++n) {
        f32x4 acc = {0.f, 0.f, 0.f, 0.f};
        #pragma unroll
        for (int kk = 0; kk < 4; ++kk) {
            const bf16x8 b = Bs[(n * 4 + kk) * 64 + lane];   // stride-1, conflict-free
            acc = __builtin_amdgcn_mfma_f32_16x16x32_bf16(a[kk], b, acc, 0, 0, 0);
        }
        #pragma unroll
        for (int i = 0; i < 4; ++i) {
            const int r = rC0 + i;
            if (r < NN)
                h_bf[(size_t)r * DIM + n * 16 + col] = (unsigned short)f2bf(acc[i]);
        }
    }
}

// ---------------------------------------------------------------- gather + epilogue
// 16 lanes per dst node (one ushort8 = 16B/lane covers 8 of 128 cols).
// 4-deep unroll: four independent 256B row gathers in flight. fp32 accumulate.
__global__ __launch_bounds__(256) void k_gather(const int* __restrict__ row_ptr,
                                                const int* __restrict__ srt,
                                                const unsigned short* __restrict__ h_bf,
                                                const float* __restrict__ dinv,
                                                const float* __restrict__ bias,
                                                float* __restrict__ out) {
    const int t = blockIdx.x * 256 + threadIdx.x;
    const int n = t >> 4;
    if (n >= NN) return;
    const int lane = t & 15;                     // columns lane*8 .. lane*8+7
    const u16x8* __restrict__ h8 = reinterpret_cast<const u16x8*>(h_bf);

    const float did = dinv[n];
    const float sn = did * did;
    float acc[8];
    {
        const u16x8 hv = h8[(size_t)n * 16 + lane];
        #pragma unroll
        for (int j = 0; j < 8; ++j) acc[j] = bf2f(hv[j]) * sn;
    }

    int p = row_ptr[n];
    const int pe = row_ptr[n + 1];
    for (; p + 3 < pe; p += 4) {
        const int s0 = srt[p],     s1 = srt[p + 1];
        const int s2 = srt[p + 2], s3 = srt[p + 3];
        const float n0 = dinv[s0] * did;
        const float n1 = dinv[s1] * did;
        const float n2 = dinv[s2] * did;
        const float n3 = dinv[s3] * did;
        const u16x8 v0 = h8[(size_t)s0 * 16 + lane];
        const u16x8 v1 = h8[(size_t)s1 * 16 + lane];
        const u16x8 v2 = h8[(size_t)s2 * 16 + lane];
        const u16x8 v3 = h8[(size_t)s3 * 16 + lane];
        #pragma unroll
        for (int j = 0; j < 8; ++j) acc[j] = fmaf(bf2f(v0[j]), n0, acc[j]);
        #pragma unroll
        for (int j = 0; j < 8; ++j) acc[j] = fmaf(bf2f(v1[j]), n1, acc[j]);
        #pragma unroll
        for (int j = 0; j < 8; ++j) acc[j] = fmaf(bf2f(v2[j]), n2, acc[j]);
        #pragma unroll
        for (int j = 0; j < 8; ++j) acc[j] = fmaf(bf2f(v3[j]), n3, acc[j]);
    }
    for (; p < pe; ++p) {
        const int s0 = srt[p];
        const float n0 = dinv[s0] * did;
        const u16x8 v0 = h8[(size_t)s0 * 16 + lane];
        #pragma unroll
        for (int j = 0; j < 8; ++j) acc[j] = fmaf(bf2f(v0[j]), n0, acc[j]);
    }

    const float4 bv0 = reinterpret_cast<const float4*>(bias)[lane * 2];
    const float4 bv1 = reinterpret_cast<const float4*>(bias)[lane * 2 + 1];
    float4 o0, o1;
    o0.x = fmaxf(acc[0] + bv0.x, 0.f); o0.y = fmaxf(acc[1] + bv0.y, 0.f);
    o0.z = fmaxf(acc[2] + bv0.z, 0.f); o0.w = fmaxf(acc[3] + bv0.w, 0.f);
    o1.x = fmaxf(acc[4] + bv1.x, 0.f); o1.y = fmaxf(acc[5] + bv1.y, 0.f);
    o1.z = fmaxf(acc[6] + bv1.z, 0.f); o1.w = fmaxf(acc[7] + bv1.w, 0.f);
    float4* orow = reinterpret_cast<float4*>(out + (size_t)n * DIM) + lane * 2;
    orow[0] = o0;
    orow[1] = o1;
}

// ----------------------------------------------------------------
extern "C" void kernel_launch(void* const* d_in, const int* in_sizes, int n_in,
                              void* d_out, int out_size, void* d_ws, size_t ws_size,
                              hipStream_t stream) {
    const float* x  = (const float*)d_in[0];
    const int*   ei = (const int*)d_in[1];   // [2, NE]: src row then dst row
    const float* W  = (const float*)d_in[2];
    const float* b  = (const float*)d_in[3];
    float* out = (float*)d_out;

    const int* src = ei;
    const int* dst = ei + NE;

    // workspace (~16.2 MB), all segments 16B-aligned:
    // h_bf [NN*DIM u16] | dinv [NN f32] | cnt/cursor [NN i32] | row_ptr [NN+4 i32]
    // | partials [NB i32] | srt [NE i32] | Wf [2048 x 16B]
    unsigned short* h_bf = (unsigned short*)d_ws;
    float* dinv     = (float*)(h_bf + (size_t)NN * DIM);
    int*   cnt      = (int*)(dinv + NN);
    int*   row_ptr  = cnt + NN;
    int*   partials = row_ptr + NN + 4;
    int*   srt      = partials + NB;
    bf16x8* Wf      = (bf16x8*)(srt + NE);

    k_init<<<49, 256, 0, stream>>>(W, Wf, (int4*)cnt);
    k_hist<<<(NE + 255) / 256, 256, 0, stream>>>(dst, cnt);
    k_scanA<<<NB, 256, 0, stream>>>(cnt, row_ptr, partials, dinv);
    k_scanC<<<NB, 256, 0, stream>>>(row_ptr, partials, cnt);
    k_fill<<<(NE + 255) / 256, 256, 0, stream>>>(src, dst, cnt, srt);
    k_gemm<<<(NN + 63) / 64, 256, 0, stream>>>(x, Wf, h_bf);
    k_gather<<<(NN * 16 + 255) / 256, 256, 0, stream>>>(row_ptr, srt, h_bf, dinv, b, out);
}

// Round 9
// 116.685 us; speedup vs baseline: 10.2185x; 1.0104x over previous
//
#include <hip/hip_runtime.h>
#include <cstdint>

#define NN 50000
#define NE 640000
#define DIM 128
#define NB ((NN + 255) / 256)            // 196 alloc blocks
#define GEMM_BLOCKS ((NN + 63) / 64)     // 782
#define HIST_BLOCKS (NE / 4 / 256)       // 625 (4 edges/thread, exact)

typedef __attribute__((ext_vector_type(8))) short bf16x8;
typedef __attribute__((ext_vector_type(8))) unsigned short u16x8;
typedef __attribute__((ext_vector_type(4))) float f32x4;

static __device__ __forceinline__ short f2bf(float f) {
    union { float f; uint32_t u; } v; v.f = f;
    uint32_t r = v.u + 0x7FFFu + ((v.u >> 16) & 1u);   // RNE
    return (short)(r >> 16);
}
static __device__ __forceinline__ float bf2f(unsigned short u) {
    union { uint32_t u; float f; } v; v.u = ((uint32_t)u) << 16;   // exact
    return v.f;
}

// ---------------------------------------------------------------- init
// Zero cnt (12500 int4 stores) + zero the bump counter + build
// fragment-ordered bf16 W. Wf[t], t=(n*4+kk)*64+lane: 8 bf16 =
// W[k0..k0+8)[n*16+(lane&15)], k0=kk*32+(lane>>4)*8 — same slot->k
// bijection as the A-side load in the gemm.
__global__ __launch_bounds__(256) void k_init(const float* __restrict__ W,
                                              bf16x8* __restrict__ Wf,
                                              int4* __restrict__ cnt4,
                                              int* __restrict__ total) {
    const int t = blockIdx.x * 256 + threadIdx.x;
    if (t < NN / 4) cnt4[t] = make_int4(0, 0, 0, 0);
    if (t == 0) *total = 0;
    if (t < 2048) {
        const int n = t >> 8;
        const int kk = (t >> 6) & 3;
        const int l = t & 63;
        const int c = n * 16 + (l & 15);
        const int k0 = kk * 32 + (l >> 4) * 8;
        bf16x8 v;
        #pragma unroll
        for (int j = 0; j < 8; ++j) v[j] = f2bf(W[(size_t)(k0 + j) * DIM + c]);
        Wf[t] = v;
    }
}

// ---------------------------------------------------------------- gemm + hist (fused)
// Independent phases share one dispatch: blocks [0,GEMM_BLOCKS) run the MFMA
// GEMM (h = x@W, bf16 out); blocks [GEMM_BLOCKS, +HIST_BLOCKS) histogram dst
// (4 edges/thread via int4). Atomic-bound hist hides under the gemm.
__global__ __launch_bounds__(256) void k_gemm_hist(const float* __restrict__ x,
                                                   const bf16x8* __restrict__ Wf,
                                                   unsigned short* __restrict__ h_bf,
                                                   const int4* __restrict__ dst4,
                                                   int* __restrict__ cnt) {
    __shared__ bf16x8 Bs[2048];   // 32 KB (allocated for hist blocks too; they
                                  // are atomic-bound, occupancy loss is moot)
    const int tid = threadIdx.x;

    if (blockIdx.x >= GEMM_BLOCKS) {
        const int i = (blockIdx.x - GEMM_BLOCKS) * 256 + tid;   // < NE/4 exact
        const int4 d = dst4[i];
        atomicAdd(&cnt[d.x], 1);
        atomicAdd(&cnt[d.y], 1);
        atomicAdd(&cnt[d.z], 1);
        atomicAdd(&cnt[d.w], 1);
        return;
    }

    #pragma unroll
    for (int i = 0; i < 8; ++i) Bs[tid + i * 256] = Wf[tid + i * 256];

    const int wave = tid >> 6;
    const int lane = tid & 63;
    const int rbase = blockIdx.x * 64 + wave * 16;
    const int rA = rbase + (lane & 15);          // A-fragment row (m = lane&15)
    const int kg = lane >> 4;                    // k-group 0..3

    bf16x8 a[4];
    if (rA < NN) {
        const float* xr = x + (size_t)rA * DIM + kg * 8;
        #pragma unroll
        for (int kk = 0; kk < 4; ++kk) {
            const float4 f0 = *reinterpret_cast<const float4*>(xr + kk * 32);
            const float4 f1 = *reinterpret_cast<const float4*>(xr + kk * 32 + 4);
            a[kk][0] = f2bf(f0.x); a[kk][1] = f2bf(f0.y);
            a[kk][2] = f2bf(f0.z); a[kk][3] = f2bf(f0.w);
            a[kk][4] = f2bf(f1.x); a[kk][5] = f2bf(f1.y);
            a[kk][6] = f2bf(f1.z); a[kk][7] = f2bf(f1.w);
        }
    } else {
        #pragma unroll
        for (int kk = 0; kk < 4; ++kk) a[kk] = (bf16x8)0;
    }
    __syncthreads();

    const int rC0 = rbase + (lane >> 4) * 4;     // C rows: rC0 + i  (i=0..3)
    const int col = lane & 15;
    #pragma unroll
    for (int n = 0; n < 8; ++n) {
        f32x4 acc = {0.f, 0.f, 0.f, 0.f};
        #pragma unroll
        for (int kk = 0; kk < 4; ++kk) {
            const bf16x8 b = Bs[(n * 4 + kk) * 64 + lane];   // stride-1, conflict-free
            acc = __builtin_amdgcn_mfma_f32_16x16x32_bf16(a[kk], b, acc, 0, 0, 0);
        }
        #pragma unroll
        for (int i = 0; i < 4; ++i) {
            const int r = rC0 + i;
            if (r < NN)
                h_bf[(size_t)r * DIM + n * 16 + col] = (unsigned short)f2bf(acc[i]);
        }
    }
}

// ---------------------------------------------------------------- bucket allocation
// Replaces the two-phase scan: per-wave shuffle exclusive-scan of 64 counts,
// one atomicAdd on a single bump counter per wave (781 total), base broadcast.
// Bucket order in srt is arbitrary — gather only needs [row_ptr[n], cnt_after
// _fill[n]) to be node n's contiguous segment. Fused: dinv = rsqrt(cnt+1).
__global__ __launch_bounds__(256) void k_alloc(int* __restrict__ cnt,
                                               int* __restrict__ row_ptr,
                                               float* __restrict__ dinv,
                                               int* __restrict__ total) {
    const int i = blockIdx.x * 256 + threadIdx.x;
    const int lane = threadIdx.x & 63;
    const int c = (i < NN) ? cnt[i] : 0;
    if (i < NN) dinv[i] = rsqrtf((float)c + 1.0f);

    int pref = c;                                 // inclusive wave scan
    #pragma unroll
    for (int off = 1; off < 64; off <<= 1) {
        int t = __shfl_up(pref, off, 64);
        if (lane >= off) pref += t;
    }
    int base = 0;
    if (lane == 63) base = atomicAdd(total, pref);  // pref@63 = wave total
    base = __shfl(base, 63, 64);

    if (i < NN) {
        const int rp = base + pref - c;           // exclusive prefix + base
        row_ptr[i] = rp;
        cnt[i] = rp;                              // becomes fill cursor
    }
}

// ---------------------------------------------------------------- bucket fill
// 4 edges/thread via int4. After this kernel, cnt[n] == row_ptr[n] + deg(n),
// i.e. the segment end — gather reads it as pe.
__global__ __launch_bounds__(256) void k_fill(const int4* __restrict__ src4,
                                              const int4* __restrict__ dst4,
                                              int* __restrict__ cursor,
                                              int* __restrict__ srt) {
    const int i = blockIdx.x * 256 + threadIdx.x;   // < NE/4 exact
    const int4 s = src4[i];
    const int4 d = dst4[i];
    srt[atomicAdd(&cursor[d.x], 1)] = s.x;
    srt[atomicAdd(&cursor[d.y], 1)] = s.y;
    srt[atomicAdd(&cursor[d.z], 1)] = s.z;
    srt[atomicAdd(&cursor[d.w], 1)] = s.w;
}

// ---------------------------------------------------------------- gather + epilogue
// 16 lanes per dst node (one ushort8 = 16B/lane covers 8 of 128 cols).
// 4-deep unroll: four independent 256B row gathers in flight. fp32 accumulate.
__global__ __launch_bounds__(256) void k_gather(const int* __restrict__ row_ptr,
                                                const int* __restrict__ seg_end,
                                                const int* __restrict__ srt,
                                                const unsigned short* __restrict__ h_bf,
                                                const float* __restrict__ dinv,
                                                const float* __restrict__ bias,
                                                float* __restrict__ out) {
    const int t = blockIdx.x * 256 + threadIdx.x;
    const int n = t >> 4;
    if (n >= NN) return;
    const int lane = t & 15;                     // columns lane*8 .. lane*8+7
    const u16x8* __restrict__ h8 = reinterpret_cast<const u16x8*>(h_bf);

    const float did = dinv[n];
    const float sn = did * did;
    float acc[8];
    {
        const u16x8 hv = h8[(size_t)n * 16 + lane];
        #pragma unroll
        for (int j = 0; j < 8; ++j) acc[j] = bf2f(hv[j]) * sn;
    }

    int p = row_ptr[n];
    const int pe = seg_end[n];
    for (; p + 3 < pe; p += 4) {
        const int s0 = srt[p],     s1 = srt[p + 1];
        const int s2 = srt[p + 2], s3 = srt[p + 3];
        const float n0 = dinv[s0] * did;
        const float n1 = dinv[s1] * did;
        const float n2 = dinv[s2] * did;
        const float n3 = dinv[s3] * did;
        const u16x8 v0 = h8[(size_t)s0 * 16 + lane];
        const u16x8 v1 = h8[(size_t)s1 * 16 + lane];
        const u16x8 v2 = h8[(size_t)s2 * 16 + lane];
        const u16x8 v3 = h8[(size_t)s3 * 16 + lane];
        #pragma unroll
        for (int j = 0; j < 8; ++j) acc[j] = fmaf(bf2f(v0[j]), n0, acc[j]);
        #pragma unroll
        for (int j = 0; j < 8; ++j) acc[j] = fmaf(bf2f(v1[j]), n1, acc[j]);
        #pragma unroll
        for (int j = 0; j < 8; ++j) acc[j] = fmaf(bf2f(v2[j]), n2, acc[j]);
        #pragma unroll
        for (int j = 0; j < 8; ++j) acc[j] = fmaf(bf2f(v3[j]), n3, acc[j]);
    }
    for (; p < pe; ++p) {
        const int s0 = srt[p];
        const float n0 = dinv[s0] * did;
        const u16x8 v0 = h8[(size_t)s0 * 16 + lane];
        #pragma unroll
        for (int j = 0; j < 8; ++j) acc[j] = fmaf(bf2f(v0[j]), n0, acc[j]);
    }

    const float4 bv0 = reinterpret_cast<const float4*>(bias)[lane * 2];
    const float4 bv1 = reinterpret_cast<const float4*>(bias)[lane * 2 + 1];
    float4 o0, o1;
    o0.x = fmaxf(acc[0] + bv0.x, 0.f); o0.y = fmaxf(acc[1] + bv0.y, 0.f);
    o0.z = fmaxf(acc[2] + bv0.z, 0.f); o0.w = fmaxf(acc[3] + bv0.w, 0.f);
    o1.x = fmaxf(acc[4] + bv1.x, 0.f); o1.y = fmaxf(acc[5] + bv1.y, 0.f);
    o1.z = fmaxf(acc[6] + bv1.z, 0.f); o1.w = fmaxf(acc[7] + bv1.w, 0.f);
    float4* orow = reinterpret_cast<float4*>(out + (size_t)n * DIM) + lane * 2;
    orow[0] = o0;
    orow[1] = o1;
}

// ----------------------------------------------------------------
extern "C" void kernel_launch(void* const* d_in, const int* in_sizes, int n_in,
                              void* d_out, int out_size, void* d_ws, size_t ws_size,
                              hipStream_t stream) {
    const float* x  = (const float*)d_in[0];
    const int*   ei = (const int*)d_in[1];   // [2, NE]: src row then dst row
    const float* W  = (const float*)d_in[2];
    const float* b  = (const float*)d_in[3];
    float* out = (float*)d_out;

    const int* src = ei;
    const int* dst = ei + NE;

    // workspace (~16.1 MB), all segments 16B-aligned:
    // h_bf [NN*DIM u16] | dinv [NN f32] | cnt/cursor/seg_end [NN i32]
    // | row_ptr [NN i32] | total [4 i32] | srt [NE i32] | Wf [2048 x 16B]
    unsigned short* h_bf = (unsigned short*)d_ws;
    float* dinv     = (float*)(h_bf + (size_t)NN * DIM);
    int*   cnt      = (int*)(dinv + NN);
    int*   row_ptr  = cnt + NN;
    int*   total    = row_ptr + NN;
    int*   srt      = total + 4;
    bf16x8* Wf      = (bf16x8*)(srt + NE);

    k_init<<<49, 256, 0, stream>>>(W, Wf, (int4*)cnt, total);
    k_gemm_hist<<<GEMM_BLOCKS + HIST_BLOCKS, 256, 0, stream>>>(
        x, Wf, h_bf, (const int4*)dst, cnt);
    k_alloc<<<NB, 256, 0, stream>>>(cnt, row_ptr, dinv, total);
    k_fill<<<HIST_BLOCKS, 256, 0, stream>>>((const int4*)src, (const int4*)dst, cnt, srt);
    k_gather<<<(NN * 16 + 255) / 256, 256, 0, stream>>>(
        row_ptr, cnt, srt, h_bf, dinv, b, out);
}

// Round 10
// 115.936 us; speedup vs baseline: 10.2845x; 1.0065x over previous
//
#include <hip/hip_runtime.h>
#include <cstdint>

#define NN 50000
#define NE 640000
#define DIM 128
#define NB ((NN + 255) / 256)            // 196 alloc blocks
#define GEMM_BLOCKS ((NN + 63) / 64)     // 782
#define HIST_BLOCKS (NE / 4 / 256)       // 625 (4 edges/thread, exact)

typedef __attribute__((ext_vector_type(8))) short bf16x8;
typedef __attribute__((ext_vector_type(8))) unsigned short u16x8;
typedef __attribute__((ext_vector_type(4))) float f32x4;

static __device__ __forceinline__ short f2bf(float f) {
    union { float f; uint32_t u; } v; v.f = f;
    uint32_t r = v.u + 0x7FFFu + ((v.u >> 16) & 1u);   // RNE
    return (short)(r >> 16);
}
static __device__ __forceinline__ float bf2f(unsigned short u) {
    union { uint32_t u; float f; } v; v.u = ((uint32_t)u) << 16;   // exact
    return v.f;
}

// ---------------------------------------------------------------- init
// Zero cnt (12500 int4 stores) + bump counter + build fragment-ordered bf16 W.
// Wf[t], t=(n*4+kk)*64+lane: 8 bf16 = W[k0..k0+8)[n*16+(lane&15)],
// k0=kk*32+(lane>>4)*8 — same slot->k bijection as the A-side load in the gemm.
__global__ __launch_bounds__(256) void k_init(const float* __restrict__ W,
                                              bf16x8* __restrict__ Wf,
                                              int4* __restrict__ cnt4,
                                              int* __restrict__ total) {
    const int t = blockIdx.x * 256 + threadIdx.x;
    if (t < NN / 4) cnt4[t] = make_int4(0, 0, 0, 0);
    if (t == 0) *total = 0;
    if (t < 2048) {
        const int n = t >> 8;
        const int kk = (t >> 6) & 3;
        const int l = t & 63;
        const int c = n * 16 + (l & 15);
        const int k0 = kk * 32 + (l >> 4) * 8;
        bf16x8 v;
        #pragma unroll
        for (int j = 0; j < 8; ++j) v[j] = f2bf(W[(size_t)(k0 + j) * DIM + c]);
        Wf[t] = v;
    }
}

// ---------------------------------------------------------------- histogram
// Standalone again: 0 LDS, 8 VGPR -> full occupancy for atomic latency hiding.
__global__ __launch_bounds__(256) void k_hist(const int4* __restrict__ dst4,
                                              int* __restrict__ cnt) {
    const int i = blockIdx.x * 256 + threadIdx.x;   // < NE/4 exact
    const int4 d = dst4[i];
    atomicAdd(&cnt[d.x], 1);
    atomicAdd(&cnt[d.y], 1);
    atomicAdd(&cnt[d.z], 1);
    atomicAdd(&cnt[d.w], 1);
}

// ---------------------------------------------------------------- bucket allocation
// Per-wave shuffle exclusive-scan of 64 counts, one atomicAdd on a global bump
// counter per wave (781 total), base broadcast. Segment order is arbitrary —
// gather only needs [row_ptr[n], end[n]) contiguous. Fused: dinv = rsqrt(cnt+1).
__global__ __launch_bounds__(256) void k_alloc(int* __restrict__ cnt,
                                               int* __restrict__ row_ptr,
                                               float* __restrict__ dinv,
                                               int* __restrict__ total) {
    const int i = blockIdx.x * 256 + threadIdx.x;
    const int lane = threadIdx.x & 63;
    const int c = (i < NN) ? cnt[i] : 0;
    if (i < NN) dinv[i] = rsqrtf((float)c + 1.0f);

    int pref = c;                                 // inclusive wave scan
    #pragma unroll
    for (int off = 1; off < 64; off <<= 1) {
        int t = __shfl_up(pref, off, 64);
        if (lane >= off) pref += t;
    }
    int base = 0;
    if (lane == 63) base = atomicAdd(total, pref);  // pref@63 = wave total
    base = __shfl(base, 63, 64);

    if (i < NN) {
        const int rp = base + pref - c;           // exclusive prefix + base
        row_ptr[i] = rp;
        cnt[i] = rp;                              // becomes fill cursor
    }
}

// ---------------------------------------------------------------- gemm + fill (fused)
// Every block: (a) MFMA tile h'[64 rows] = (dinv*x) @ W stored bf16 — the
// dinv[src] factor is folded into h' so gather needs no per-edge scaling;
// (b) <=4 fill edges/thread: loads issued at kernel start, atomic+scatter
// after the MFMA store so their latency hides under compute. No occupancy
// asymmetry: all blocks are identical.
__global__ __launch_bounds__(256) void k_gemm_fill(const float* __restrict__ x,
                                                   const bf16x8* __restrict__ Wf,
                                                   const float* __restrict__ dinv,
                                                   unsigned short* __restrict__ h_bf,
                                                   const int4* __restrict__ src4,
                                                   const int4* __restrict__ dst4,
                                                   int* __restrict__ cursor,
                                                   int* __restrict__ srt) {
    __shared__ bf16x8 Bs[2048];   // 32 KB
    const int tid = threadIdx.x;

    // fill edge loads — issue first, consume last
    const int ei = blockIdx.x * 256 + tid;
    const bool has_edge = (ei < NE / 4);
    int4 es = make_int4(0, 0, 0, 0), ed = make_int4(0, 0, 0, 0);
    if (has_edge) { es = src4[ei]; ed = dst4[ei]; }

    #pragma unroll
    for (int i = 0; i < 8; ++i) Bs[tid + i * 256] = Wf[tid + i * 256];

    const int wave = tid >> 6;
    const int lane = tid & 63;
    const int rbase = blockIdx.x * 64 + wave * 16;
    const int rA = rbase + (lane & 15);          // A-fragment row (m = lane&15)
    const int kg = lane >> 4;                    // k-group 0..3

    bf16x8 a[4];
    if (rA < NN) {
        const float ds = dinv[rA];               // fold dinv[src] into h'
        const float* xr = x + (size_t)rA * DIM + kg * 8;
        #pragma unroll
        for (int kk = 0; kk < 4; ++kk) {
            const float4 f0 = *reinterpret_cast<const float4*>(xr + kk * 32);
            const float4 f1 = *reinterpret_cast<const float4*>(xr + kk * 32 + 4);
            a[kk][0] = f2bf(f0.x * ds); a[kk][1] = f2bf(f0.y * ds);
            a[kk][2] = f2bf(f0.z * ds); a[kk][3] = f2bf(f0.w * ds);
            a[kk][4] = f2bf(f1.x * ds); a[kk][5] = f2bf(f1.y * ds);
            a[kk][6] = f2bf(f1.z * ds); a[kk][7] = f2bf(f1.w * ds);
        }
    } else {
        #pragma unroll
        for (int kk = 0; kk < 4; ++kk) a[kk] = (bf16x8)0;
    }
    __syncthreads();

    const int rC0 = rbase + (lane >> 4) * 4;     // C rows: rC0 + i  (i=0..3)
    const int col = lane & 15;
    #pragma unroll
    for (int n = 0; n < 8; ++n) {
        f32x4 acc = {0.f, 0.f, 0.f, 0.f};
        #pragma unroll
        for (int kk = 0; kk < 4; ++kk) {
            const bf16x8 b = Bs[(n * 4 + kk) * 64 + lane];   // stride-1, conflict-free
            acc = __builtin_amdgcn_mfma_f32_16x16x32_bf16(a[kk], b, acc, 0, 0, 0);
        }
        #pragma unroll
        for (int i = 0; i < 4; ++i) {
            const int r = rC0 + i;
            if (r < NN)
                h_bf[(size_t)r * DIM + n * 16 + col] = (unsigned short)f2bf(acc[i]);
        }
    }

    // fill: 4 independent atomic->scatter chains, latency overlapped with
    // other waves' compute / C-stores
    if (has_edge) {
        srt[atomicAdd(&cursor[ed.x], 1)] = es.x;
        srt[atomicAdd(&cursor[ed.y], 1)] = es.y;
        srt[atomicAdd(&cursor[ed.z], 1)] = es.z;
        srt[atomicAdd(&cursor[ed.w], 1)] = es.w;
    }
}

// ---------------------------------------------------------------- gather + epilogue
// 16 lanes per dst node (ushort8 = 16B/lane covers 8 of 128 cols). h' already
// carries dinv[src], so the inner loop is a pure bf16 row-sum; one did* at the
// end covers both edge terms and the self loop. 4-deep MLP unroll.
__global__ __launch_bounds__(256) void k_gather(const int* __restrict__ row_ptr,
                                                const int* __restrict__ seg_end,
                                                const int* __restrict__ srt,
                                                const unsigned short* __restrict__ h_bf,
                                                const float* __restrict__ dinv,
                                                const float* __restrict__ bias,
                                                float* __restrict__ out) {
    const int t = blockIdx.x * 256 + threadIdx.x;
    const int n = t >> 4;
    if (n >= NN) return;
    const int lane = t & 15;                     // columns lane*8 .. lane*8+7
    const u16x8* __restrict__ h8 = reinterpret_cast<const u16x8*>(h_bf);

    float acc[8];
    {
        const u16x8 hv = h8[(size_t)n * 16 + lane];   // self loop: h'[n]
        #pragma unroll
        for (int j = 0; j < 8; ++j) acc[j] = bf2f(hv[j]);
    }

    int p = row_ptr[n];
    const int pe = seg_end[n];
    for (; p + 3 < pe; p += 4) {
        const int s0 = srt[p],     s1 = srt[p + 1];
        const int s2 = srt[p + 2], s3 = srt[p + 3];
        const u16x8 v0 = h8[(size_t)s0 * 16 + lane];
        const u16x8 v1 = h8[(size_t)s1 * 16 + lane];
        const u16x8 v2 = h8[(size_t)s2 * 16 + lane];
        const u16x8 v3 = h8[(size_t)s3 * 16 + lane];
        #pragma unroll
        for (int j = 0; j < 8; ++j) acc[j] += bf2f(v0[j]);
        #pragma unroll
        for (int j = 0; j < 8; ++j) acc[j] += bf2f(v1[j]);
        #pragma unroll
        for (int j = 0; j < 8; ++j) acc[j] += bf2f(v2[j]);
        #pragma unroll
        for (int j = 0; j < 8; ++j) acc[j] += bf2f(v3[j]);
    }
    for (; p < pe; ++p) {
        const u16x8 v0 = h8[(size_t)srt[p] * 16 + lane];
        #pragma unroll
        for (int j = 0; j < 8; ++j) acc[j] += bf2f(v0[j]);
    }

    const float did = dinv[n];
    const float4 bv0 = reinterpret_cast<const float4*>(bias)[lane * 2];
    const float4 bv1 = reinterpret_cast<const float4*>(bias)[lane * 2 + 1];
    float4 o0, o1;
    o0.x = fmaxf(fmaf(did, acc[0], bv0.x), 0.f);
    o0.y = fmaxf(fmaf(did, acc[1], bv0.y), 0.f);
    o0.z = fmaxf(fmaf(did, acc[2], bv0.z), 0.f);
    o0.w = fmaxf(fmaf(did, acc[3], bv0.w), 0.f);
    o1.x = fmaxf(fmaf(did, acc[4], bv1.x), 0.f);
    o1.y = fmaxf(fmaf(did, acc[5], bv1.y), 0.f);
    o1.z = fmaxf(fmaf(did, acc[6], bv1.z), 0.f);
    o1.w = fmaxf(fmaf(did, acc[7], bv1.w), 0.f);
    float4* orow = reinterpret_cast<float4*>(out + (size_t)n * DIM) + lane * 2;
    orow[0] = o0;
    orow[1] = o1;
}

// ----------------------------------------------------------------
extern "C" void kernel_launch(void* const* d_in, const int* in_sizes, int n_in,
                              void* d_out, int out_size, void* d_ws, size_t ws_size,
                              hipStream_t stream) {
    const float* x  = (const float*)d_in[0];
    const int*   ei = (const int*)d_in[1];   // [2, NE]: src row then dst row
    const float* W  = (const float*)d_in[2];
    const float* b  = (const float*)d_in[3];
    float* out = (float*)d_out;

    const int* src = ei;
    const int* dst = ei + NE;

    // workspace (~16.1 MB), all segments 16B-aligned:
    // h_bf [NN*DIM u16] | dinv [NN f32] | cnt/cursor/seg_end [NN i32]
    // | row_ptr [NN i32] | total [4 i32] | srt [NE i32] | Wf [2048 x 16B]
    unsigned short* h_bf = (unsigned short*)d_ws;
    float* dinv     = (float*)(h_bf + (size_t)NN * DIM);
    int*   cnt      = (int*)(dinv + NN);
    int*   row_ptr  = cnt + NN;
    int*   total    = row_ptr + NN;
    int*   srt      = total + 4;
    bf16x8* Wf      = (bf16x8*)(srt + NE);

    k_init<<<49, 256, 0, stream>>>(W, Wf, (int4*)cnt, total);
    k_hist<<<HIST_BLOCKS, 256, 0, stream>>>((const int4*)dst, cnt);
    k_alloc<<<NB, 256, 0, stream>>>(cnt, row_ptr, dinv, total);
    k_gemm_fill<<<GEMM_BLOCKS, 256, 0, stream>>>(
        x, Wf, dinv, h_bf, (const int4*)src, (const int4*)dst, cnt, srt);
    k_gather<<<(NN * 16 + 255) / 256, 256, 0, stream>>>(
        row_ptr, cnt, srt, h_bf, dinv, b, out);
}